// Round 6
// baseline (817.875 us; speedup 1.0000x reference)
//
#include <hip/hip_runtime.h>
#include <stdint.h>
#include <stddef.h>

// ---------------- problem constants ----------------
#define N_NODES  4096
#define N_EDGES  12288
#define EA_EDGES 16384      // N_EDGES + N_NODES self loops
#define NBATCH   64
#define CLIPD    768
#define HIDD     1024
#define C2D      3072
#define NEG_SLOPE 0.2f
#define MAXDEG   96         // in-degree ~Poisson(3); P(>96) ~ 0

typedef unsigned short u16;
typedef short bf16x8 __attribute__((ext_vector_type(8)));   // 8 bf16 = 4 VGPRs (guide §3)
typedef float f32x4  __attribute__((ext_vector_type(4)));

static __device__ __forceinline__ float b2f(u16 u) {
    union { float f; unsigned int i; } v; v.i = ((unsigned int)u) << 16; return v.f;
}
static __device__ __forceinline__ u16 f2b(float f) {
    union { float f; unsigned int i; } v; v.f = f;
    unsigned int r = (v.i + 0x7fffu + ((v.i >> 16) & 1u)) >> 16;   // RNE
    return (u16)r;
}
// dtype-polymorphic element load (inputs are fp32; internal tensors bf16)
static __device__ __forceinline__ float ldv(const float* p, size_t i) { return p[i]; }
static __device__ __forceinline__ float ldv(const u16* p, size_t i)   { return b2f(p[i]); }

static __device__ __forceinline__ float wsum(float v) {
#pragma unroll
    for (int o = 32; o > 0; o >>= 1) v += __shfl_xor(v, o, 64);
    return v;
}
static __device__ __forceinline__ float wmax(float v) {
#pragma unroll
    for (int o = 32; o > 0; o >>= 1) v = fmaxf(v, __shfl_xor(v, o, 64));
    return v;
}
static __device__ __forceinline__ int lower_bound(const int* a, int n, int key) {
    int lo = 0, hi = n;
    while (lo < hi) { int m = (lo + hi) >> 1; if (a[m] < key) lo = m + 1; else hi = m; }
    return lo;
}

// async global->LDS, 16B per lane. LDS dst is wave-uniform base + lane*16 (m104/m108);
// our LDS offsets are exactly tid*16, satisfying that constraint.
#define GLD16(gp, lp)                                                            \
    __builtin_amdgcn_global_load_lds((const __attribute__((address_space(1))) void*)(gp), \
                                     (__attribute__((address_space(3))) void*)(lp), 16, 0, 0)

// ---------------- CSR build ----------------
__global__ void k_deg(const int* __restrict__ dst, int* __restrict__ deg) {
    int e = blockIdx.x * 256 + threadIdx.x;
    if (e < N_EDGES) atomicAdd(&deg[dst[e]], 1);
}

__global__ void k_scan(const int* __restrict__ deg, int* __restrict__ offs) {
    __shared__ int s[1024];
    int t = threadIdx.x;
    int v[4]; int sum = 0;
#pragma unroll
    for (int i = 0; i < 4; i++) { v[i] = deg[t * 4 + i] + 1; sum += v[i]; }
    s[t] = sum; __syncthreads();
    for (int st = 1; st < 1024; st <<= 1) {
        int x = 0;
        if (t >= st) x = s[t - st];
        __syncthreads();
        s[t] += x;
        __syncthreads();
    }
    int run = s[t] - sum;
#pragma unroll
    for (int i = 0; i < 4; i++) { offs[t * 4 + i] = run; run += v[i]; }
    if (t == 1023) offs[N_NODES] = run;
}

__global__ void k_fill(const int* __restrict__ dst, const int* __restrict__ offs,
                       int* __restrict__ cur, int* __restrict__ csr) {
    int id = blockIdx.x * 256 + threadIdx.x;
    if (id >= EA_EDGES) return;
    int d = (id < N_EDGES) ? dst[id] : (id - N_EDGES);
    int p = atomicAdd(&cur[d], 1);
    csr[offs[d] + p] = id;
}

// ---------------- weight-side attention reductions (fp32 in, fp32 out) ----------------
__global__ void k_reduce_w(const float* __restrict__ W, const float* __restrict__ attA,
                           const float* __restrict__ attB, float* __restrict__ out,
                           int C, int col0) {
    int d = blockIdx.x, t = threadIdx.x;
    float acc[8] = {0, 0, 0, 0, 0, 0, 0, 0};
    for (int c = t; c < C; c += 256) {
#pragma unroll
        for (int h = 0; h < 4; h++) {
            float w = W[((size_t)d * 4 + h) * C + c];
            acc[h] += w * attA[h * C + c];
            if (attB) acc[4 + h] += w * attB[h * C + c];
        }
    }
    __shared__ float red[4][8];
    int lane = t & 63, wv = t >> 6;
#pragma unroll
    for (int j = 0; j < 8; j++) acc[j] = wsum(acc[j]);
    if (lane == 0) {
#pragma unroll
        for (int j = 0; j < 8; j++) red[wv][j] = acc[j];
    }
    __syncthreads();
    if (t < 8) {
        float s = red[0][t] + red[1][t] + red[2][t] + red[3][t];
        if (attB) out[d * 8 + col0 + t] = s;
        else if (t < 4) out[d * 8 + col0 + t] = s;
    }
}

// skinny GEMV: out[row][0..7] = X[row,:] @ Wr[:,0..7]   (one wave per row)
template <typename T>
__global__ void k_gemv8(const T* __restrict__ X, int K, const float* __restrict__ Wr,
                        float* __restrict__ out, int rows) {
    int wv = threadIdx.x >> 6, lane = threadIdx.x & 63;
    int row = blockIdx.x * 4 + wv;
    if (row >= rows) return;
    float acc[8] = {0, 0, 0, 0, 0, 0, 0, 0};
    const T* xp = X + (size_t)row * K;
    for (int k = lane; k < K; k += 64) {
        float xv = ldv(xp, k);
        const float* w = Wr + (size_t)k * 8;
#pragma unroll
        for (int j = 0; j < 8; j++) acc[j] += xv * w[j];
    }
#pragma unroll
    for (int j = 0; j < 8; j++) acc[j] = wsum(acc[j]);
    if (lane == 0) {
#pragma unroll
        for (int j = 0; j < 8; j++) out[(size_t)row * 8 + j] = acc[j];
    }
}

// self-loop edge attention = mean of incident real edges' a_e (linearity of mean_attr @ w)
__global__ void k_selfloop(float* __restrict__ ae, const int* __restrict__ csr,
                           const int* __restrict__ offs, const int* __restrict__ deg) {
    int n = blockIdx.x * 256 + threadIdx.x;
    if (n >= N_NODES) return;
    float s[8] = {0, 0, 0, 0, 0, 0, 0, 0};
    int lo = offs[n], hi = offs[n + 1];
    for (int i = lo; i < hi; i++) {
        int eid = csr[i];
        if (eid < N_EDGES) {
#pragma unroll
            for (int j = 0; j < 8; j++) s[j] += ae[(size_t)eid * 8 + j];
        }
    }
    float inv = 1.0f / (float)(deg[n] > 0 ? deg[n] : 1);
#pragma unroll
    for (int j = 0; j < 8; j++) ae[(size_t)(N_EDGES + n) * 8 + j] = s[j] * inv;
}

// per-dst-node attention softmax + aggregation in INPUT feature space:
// agg[n, d*4+h] = sum_e coef[e,h] * feat[src_e, d]  (bf16 out; column order = W's natural layout)
template <typename T>
__global__ void k_attn_agg(const T* __restrict__ feat, int D,
                           const float* __restrict__ asd, const float* __restrict__ ae, int aecol,
                           const int* __restrict__ offs, const int* __restrict__ csr,
                           const int* __restrict__ src, u16* __restrict__ agg) {
    int n = blockIdx.x, t = threadIdx.x;
    __shared__ int sl[MAXDEG];
    __shared__ float cf[MAXDEG][4];
    int lo = offs[n];
    int cnt = offs[n + 1] - lo;
    if (cnt > MAXDEG) cnt = MAXDEG;
    for (int i = t; i < cnt; i += 256) {
        int eid = csr[lo + i];
        int s = (eid < N_EDGES) ? src[eid] : n;
        sl[i] = s;
#pragma unroll
        for (int h = 0; h < 4; h++) {
            float al = asd[(size_t)s * 8 + h] + asd[(size_t)n * 8 + 4 + h] +
                       ae[(size_t)eid * 8 + aecol + h];
            cf[i][h] = (al >= 0.f) ? al : NEG_SLOPE * al;
        }
    }
    __syncthreads();
    if (t < 4) {   // head t: serial softmax over <= ~20 edges
        float mx = -1e30f;
        for (int i = 0; i < cnt; i++) mx = fmaxf(mx, cf[i][t]);
        float den = 0.f;
        for (int i = 0; i < cnt; i++) { float e = __expf(cf[i][t] - mx); cf[i][t] = e; den += e; }
        float inv = 1.0f / (den + 1e-16f);
        for (int i = 0; i < cnt; i++) cf[i][t] *= inv;
    }
    __syncthreads();
    for (int d = t; d < D; d += 256) {
        float a0 = 0, a1 = 0, a2 = 0, a3 = 0;
        for (int i = 0; i < cnt; i++) {
            float v = ldv(feat, (size_t)sl[i] * D + d);
            a0 += cf[i][0] * v; a1 += cf[i][1] * v; a2 += cf[i][2] * v; a3 += cf[i][3] * v;
        }
        ushort4 pk; pk.x = f2b(a0); pk.y = f2b(a1); pk.z = f2b(a2); pk.w = f2b(a3);
        *(ushort4*)(agg + (size_t)n * 4 * D + (size_t)d * 4) = pk;
    }
}

// ---------------- transpose + downcast (fp32 [R,C] -> bf16 [C,R]) ----------------
__global__ void k_transpose(const float* __restrict__ in, u16* __restrict__ out, int R, int C) {
    __shared__ float tile[64][65];
    int tx = threadIdx.x, ty = threadIdx.y;
    int rb = blockIdx.y * 64, cb = blockIdx.x * 64;
    for (int i = ty; i < 64; i += 4) tile[i][tx] = in[(size_t)(rb + i) * C + cb + tx];
    __syncthreads();
    for (int i = ty; i < 64; i += 4) out[(size_t)(cb + i) * R + rb + tx] = f2b(tile[tx][i]);
}

// ---------------- MFMA GEMM: C = prelu(scale * A@Bt^T + bias) ----------------
// A [M,K] bf16 row-major, Bt [N,K] bf16 row-major. 128xBN tile, BK=32, 4 waves.
// Chunk mapping c -> (row = (c>>6)*16 + (c&15), kb = (c>>4)&3) satisfies BOTH pipes:
//  * staging (GLD16 at LDS offset c*16): wave w covers rows w*16..w*16+15 x all 4 kb
//    = 16 complete 64B lines/instruction (lanes {l,l+16,l+32,l+48} fetch the 4
//    consecutive 16B segments of one line) -- keeps R5's coalescing win;
//  * fragment read: lane l needs (row = blk*16+(l&15), kchunk q=l>>4) which sits at
//    chunk blk*64 + q*16 + (l&15) = blk*64 + l -> ds_read_b128 over a CONTIGUOUS
//    1024B block, same conflict-free pattern as the staging writes. R5's row-major
//    layout put rows 64B apart (8 lanes per 4-bank group -> 1.26e7 conflict cycles
//    = ~15% of kernel time); this removes that without touching staging.
template <int BN>
__global__ __launch_bounds__(256, 2) void k_gemm(
        const u16* __restrict__ A, const u16* __restrict__ Bt, void* __restrict__ Cout,
        const float* __restrict__ bias, const float* __restrict__ prelu, float scale,
        int N, int K, int f32out) {
    constexpr int NJ = BN / 32;              // 16-wide n-subtiles per wave (2 waves along N)
    __shared__ __align__(16) u16 As[4096];       // 128 rows x 32 k (chunk-mapped), 8KB
    __shared__ __align__(16) u16 Bs[BN * 32];    // BN rows x 32 k (chunk-mapped)
    int tid = threadIdx.x;
    int lane = tid & 63, wv = tid >> 6;
    int m0 = blockIdx.y * 128, n0 = blockIdx.x * BN;
    int c0 = tid, c1 = tid + 256;
    // chunk c -> row = (c>>6)*16 + (c&15), kb = (c>>4)&3
    int r0c = (c0 >> 6) * 16 + (c0 & 15), k0c = (c0 >> 4) & 3;
    int r1c = (c1 >> 6) * 16 + (c1 & 15), k1c = (c1 >> 4) & 3;
    const u16* ag0 = A + (size_t)(m0 + r0c) * K + k0c * 8;
    const u16* ag1 = A + (size_t)(m0 + r1c) * K + k1c * 8;
    const u16* bg0 = Bt + (size_t)(n0 + r0c) * K + k0c * 8;
    const u16* bg1 = Bt + (size_t)(n0 + r1c) * K + k1c * 8;   // used only when BN==128
    u16* la0 = As + c0 * 8; u16* la1 = As + c1 * 8;
    u16* lb0 = Bs + c0 * 8; u16* lb1 = Bs + c1 * 8;           // lb1 only when BN==128
    int wm = wv & 1, wn = wv >> 1;
    int rl = lane & 15;
    int q = lane >> 4;
    f32x4 acc[4][NJ] = {};
    for (int k0 = 0; k0 < K; k0 += 32) {
        __syncthreads();                       // previous tile's LDS reads done
        GLD16(ag0, la0); GLD16(ag1, la1);
        GLD16(bg0, lb0);
        if (BN == 128) GLD16(bg1, lb1);
        ag0 += 32; ag1 += 32; bg0 += 32;
        if (BN == 128) bg1 += 32;
        __syncthreads();                       // drains vmcnt(0): staging landed
        bf16x8 af[4], bfr[NJ];
#pragma unroll
        for (int i = 0; i < 4; i++)            // chunk = (wm*4+i)*64 + q*16 + rl
            af[i] = *(const bf16x8*)(As + (((wm * 4 + i) * 64 + q * 16 + rl) * 8));
#pragma unroll
        for (int j = 0; j < NJ; j++)           // chunk = (wn*NJ+j)*64 + q*16 + rl
            bfr[j] = *(const bf16x8*)(Bs + (((wn * NJ + j) * 64 + q * 16 + rl) * 8));
#pragma unroll
        for (int i = 0; i < 4; i++)
#pragma unroll
            for (int j = 0; j < NJ; j++)
                acc[i][j] = __builtin_amdgcn_mfma_f32_16x16x32_bf16(af[i], bfr[j], acc[i][j], 0, 0, 0);
    }
    float pa = prelu[0];
    int r0w = (lane >> 4) * 4;
    int cc = lane & 15;
#pragma unroll
    for (int j = 0; j < NJ; j++) {
        int col = n0 + wn * (NJ * 16) + j * 16 + cc;
        float bv = bias[col];
#pragma unroll
        for (int i = 0; i < 4; i++) {
#pragma unroll
            for (int r = 0; r < 4; r++) {
                int row = m0 + wm * 64 + i * 16 + r0w + r;
                float v = acc[i][j][r] * scale + bv;
                v = (v >= 0.f) ? v : pa * v;
                if (f32out) ((float*)Cout)[(size_t)row * N + col] = v;
                else        ((u16*)Cout)[(size_t)row * N + col] = f2b(v);
            }
        }
    }
}

// ---------------- gate + pooling ----------------
__global__ void k_gate(const float* __restrict__ g2, const float* __restrict__ gW3,
                       const float* __restrict__ gb3, float* __restrict__ gate) {
    int wv = threadIdx.x >> 6, lane = threadIdx.x & 63;
    int n = blockIdx.x * 4 + wv;
    if (n >= N_NODES) return;
    float s = 0.f;
    for (int k = lane; k < HIDD; k += 64) s += g2[(size_t)n * HIDD + k] * gW3[k];
    s = wsum(s);
    if (lane == 0) gate[n] = s + gb3[0];
}

__global__ void k_pool(const float* __restrict__ gate, const u16* __restrict__ h2,
                       const int* __restrict__ batch, float* __restrict__ out) {
    int b = blockIdx.x, t = threadIdx.x;
    int lo = lower_bound(batch, N_NODES, b);
    int hi = lower_bound(batch, N_NODES, b + 1);
    int cnt = hi - lo;
    if (cnt <= 0) {
        for (int c = t; c < C2D; c += 256) out[(size_t)b * C2D + c] = 0.f;
        return;
    }
    if (cnt > 256) cnt = 256;   // multinomial(4096,1/64) max ~110; safety clamp
    __shared__ float w[256];
    __shared__ float red[4];
    int lane = t & 63, wv = t >> 6;
    float mx = -1e30f;
    for (int i = t; i < cnt; i += 256) mx = fmaxf(mx, gate[lo + i]);
    mx = wmax(mx);
    if (lane == 0) red[wv] = mx;
    __syncthreads();
    mx = fmaxf(fmaxf(red[0], red[1]), fmaxf(red[2], red[3]));
    __syncthreads();
    float ds = 0.f;
    for (int i = t; i < cnt; i += 256) { float e = __expf(gate[lo + i] - mx); w[i] = e; ds += e; }
    ds = wsum(ds);
    if (lane == 0) red[wv] = ds;
    __syncthreads();
    float inv = 1.0f / (red[0] + red[1] + red[2] + red[3] + 1e-16f);
    for (int c = t; c < C2D; c += 256) {
        float acc = 0.f;
        for (int i = 0; i < cnt; i++) acc += w[i] * b2f(h2[(size_t)(lo + i) * C2D + c]);
        out[(size_t)b * C2D + c] = acc * inv;
    }
}

// ---------------- launch ----------------
extern "C" void kernel_launch(void* const* d_in, const int* in_sizes, int n_in,
                              void* d_out, int out_size, void* d_ws, size_t ws_size,
                              hipStream_t stream) {
    (void)in_sizes; (void)n_in; (void)out_size; (void)ws_size;
    const float* x      = (const float*)d_in[0];
    const int*   eidx   = (const int*)d_in[1];
    const float* eattr  = (const float*)d_in[2];
    const int*   batch  = (const int*)d_in[3];
    const float* W1     = (const float*)d_in[4];
    const float* att_s1 = (const float*)d_in[5];
    const float* att_d1 = (const float*)d_in[6];
    const float* We1    = (const float*)d_in[7];
    const float* att_e1 = (const float*)d_in[8];
    const float* bias1  = (const float*)d_in[9];
    const float* prelu1 = (const float*)d_in[10];
    const float* W2     = (const float*)d_in[11];
    const float* att_s2 = (const float*)d_in[12];
    const float* att_d2 = (const float*)d_in[13];
    const float* We2    = (const float*)d_in[14];
    const float* att_e2 = (const float*)d_in[15];
    const float* bias2  = (const float*)d_in[16];
    const float* prelu2 = (const float*)d_in[17];
    const float* gW1    = (const float*)d_in[18];
    const float* gb1    = (const float*)d_in[19];
    const float* ga1    = (const float*)d_in[20];
    const float* gW2    = (const float*)d_in[21];
    const float* gb2    = (const float*)d_in[22];
    const float* ga2    = (const float*)d_in[23];
    const float* gW3    = (const float*)d_in[24];
    const float* gb3    = (const float*)d_in[25];
    const int* srcA = eidx;
    const int* dstA = eidx + N_EDGES;

    // ---- workspace (unions; total ~90 MB)
    char* wp = (char*)d_ws;
    auto alloc = [&](size_t bytes) -> void* {
        void* p = (void*)wp; wp += (bytes + 255) & ~(size_t)255; return p;
    };
    int*   deg  = (int*)alloc(N_NODES * 4);
    int*   cur  = (int*)alloc(N_NODES * 4);
    int*   offs = (int*)alloc((N_NODES + 1) * 4);
    int*   csr  = (int*)alloc(EA_EDGES * 4);
    float* vsd1 = (float*)alloc(CLIPD * 8 * 4);
    float* we12 = (float*)alloc(CLIPD * 8 * 4);
    float* vsd2 = (float*)alloc(HIDD * 8 * 4);
    float* ae   = (float*)alloc((size_t)EA_EDGES * 8 * 4);
    float* asd1 = (float*)alloc((size_t)N_NODES * 8 * 4);
    float* asd2 = (float*)alloc((size_t)N_NODES * 8 * 4);
    float* gate = (float*)alloc(N_NODES * 4);
    // union 1 (32MB): agg1 [N,3072]bf16 / agg2 [N,4096]bf16 / g2 [N,1024]f32
    char*  aggU = (char*)alloc((size_t)N_NODES * 4096 * 2);
    u16*   agg1 = (u16*)aggU;
    u16*   agg2 = (u16*)aggU;
    float* g2   = (float*)aggU;
    // union 2 (8MB): h1 / g1 (h1 dead before g1 written)
    u16*   h1   = (u16*)alloc((size_t)N_NODES * HIDD * 2);
    u16*   g1   = h1;
    u16*   h2   = (u16*)alloc((size_t)N_NODES * C2D * 2);          // 24MB
    u16*   Btb  = (u16*)alloc((size_t)C2D * 4096 * 2);             // 24MB shared B^T buf

    hipMemsetAsync(deg, 0, N_NODES * 4, stream);
    hipMemsetAsync(cur, 0, N_NODES * 4, stream);

    // CSR by dst (includes self loops)
    k_deg<<<(N_EDGES + 255) / 256, 256, 0, stream>>>(dstA, deg);
    k_scan<<<1, 1024, 0, stream>>>(deg, offs);
    k_fill<<<(EA_EDGES + 255) / 256, 256, 0, stream>>>(dstA, offs, cur, csr);

    // weight-side reductions: vsd1=[W1.att_src1|W1.att_dst1], we12=[We1.att_e1|We2.att_e2], vsd2 likewise
    k_reduce_w<<<CLIPD, 256, 0, stream>>>(W1, att_s1, att_d1, vsd1, HIDD, 0);
    k_reduce_w<<<CLIPD, 256, 0, stream>>>(We1, att_e1, nullptr, we12, HIDD, 0);
    k_reduce_w<<<HIDD, 256, 0, stream>>>(W2, att_s2, att_d2, vsd2, C2D, 0);
    k_reduce_w<<<CLIPD, 256, 0, stream>>>(We2, att_e2, nullptr, we12, C2D, 4);

    // edge attention logits for both layers; self-loop rows = incident mean (linearity)
    k_gemv8<float><<<N_EDGES / 4, 256, 0, stream>>>(eattr, CLIPD, we12, ae, N_EDGES);
    k_selfloop<<<(N_NODES + 255) / 256, 256, 0, stream>>>(ae, csr, offs, deg);
    k_gemv8<float><<<N_NODES / 4, 256, 0, stream>>>(x, CLIPD, vsd1, asd1, N_NODES);

    // ---- layer 1: aggregate in input space, then one fused GEMM (head-mean=0.25, bias, prelu)
    k_attn_agg<float><<<N_NODES, 256, 0, stream>>>(x, CLIPD, asd1, ae, 0, offs, csr, srcA, agg1);
    k_transpose<<<dim3(HIDD / 64, C2D / 64), dim3(64, 4), 0, stream>>>(W1, Btb, C2D, HIDD);
    k_gemm<64><<<dim3(HIDD / 64, N_NODES / 128), 256, 0, stream>>>(
        agg1, Btb, h1, bias1, prelu1, 0.25f, HIDD, C2D, 0);

    // ---- layer 2
    k_gemv8<u16><<<N_NODES / 4, 256, 0, stream>>>(h1, HIDD, vsd2, asd2, N_NODES);
    k_attn_agg<u16><<<N_NODES, 256, 0, stream>>>(h1, HIDD, asd2, ae, 4, offs, csr, srcA, agg2);
    k_transpose<<<dim3(C2D / 64, 4096 / 64), dim3(64, 4), 0, stream>>>(W2, Btb, 4096, C2D);
    k_gemm<128><<<dim3(C2D / 128, N_NODES / 128), 256, 0, stream>>>(
        agg2, Btb, h2, bias2, prelu2, 0.25f, C2D, 4096, 0);

    // ---- gate MLP (g2 kept fp32 for the softmax path)
    k_transpose<<<dim3(HIDD / 64, C2D / 64), dim3(64, 4), 0, stream>>>(gW1, Btb, C2D, HIDD);
    k_gemm<64><<<dim3(HIDD / 64, N_NODES / 128), 256, 0, stream>>>(
        h2, Btb, g1, gb1, ga1, 1.0f, HIDD, C2D, 0);
    k_transpose<<<dim3(HIDD / 64, HIDD / 64), dim3(64, 4), 0, stream>>>(gW2, Btb, HIDD, HIDD);
    k_gemm<64><<<dim3(HIDD / 64, N_NODES / 128), 256, 0, stream>>>(
        g1, Btb, (void*)g2, gb2, ga2, 1.0f, HIDD, HIDD, 1);
    k_gate<<<N_NODES / 4, 256, 0, stream>>>(g2, gW3, gb3, gate);

    // ---- attentional pooling over sorted batch (fp32 output)
    k_pool<<<NBATCH, 256, 0, stream>>>(gate, h2, batch, (float*)d_out);
}

// Round 7
// 710.539 us; speedup vs baseline: 1.1511x; 1.1511x over previous
//
#include <hip/hip_runtime.h>
#include <stdint.h>
#include <stddef.h>

// ---------------- problem constants ----------------
#define N_NODES  4096
#define N_EDGES  12288
#define EA_EDGES 16384      // N_EDGES + N_NODES self loops
#define NBATCH   64
#define CLIPD    768
#define HIDD     1024
#define C2D      3072
#define NEG_SLOPE 0.2f
#define MAXDEG   96         // in-degree ~Poisson(3); P(>96) ~ 0

typedef unsigned short u16;
typedef short bf16x8 __attribute__((ext_vector_type(8)));   // 8 bf16 = 4 VGPRs (guide §3)
typedef float f32x4  __attribute__((ext_vector_type(4)));

static __device__ __forceinline__ float b2f(u16 u) {
    union { float f; unsigned int i; } v; v.i = ((unsigned int)u) << 16; return v.f;
}
static __device__ __forceinline__ u16 f2b(float f) {
    union { float f; unsigned int i; } v; v.f = f;
    unsigned int r = (v.i + 0x7fffu + ((v.i >> 16) & 1u)) >> 16;   // RNE
    return (u16)r;
}
// dtype-polymorphic element load (inputs are fp32; internal tensors bf16)
static __device__ __forceinline__ float ldv(const float* p, size_t i) { return p[i]; }
static __device__ __forceinline__ float ldv(const u16* p, size_t i)   { return b2f(p[i]); }

static __device__ __forceinline__ float wsum(float v) {
#pragma unroll
    for (int o = 32; o > 0; o >>= 1) v += __shfl_xor(v, o, 64);
    return v;
}
static __device__ __forceinline__ float wmax(float v) {
#pragma unroll
    for (int o = 32; o > 0; o >>= 1) v = fmaxf(v, __shfl_xor(v, o, 64));
    return v;
}
static __device__ __forceinline__ int lower_bound(const int* a, int n, int key) {
    int lo = 0, hi = n;
    while (lo < hi) { int m = (lo + hi) >> 1; if (a[m] < key) lo = m + 1; else hi = m; }
    return lo;
}

// async global->LDS, 16B per lane. LDS dst is wave-uniform base + lane*16 (m104/m108);
// our LDS offsets are exactly tid*16, satisfying that constraint.
#define GLD16(gp, lp)                                                            \
    __builtin_amdgcn_global_load_lds((const __attribute__((address_space(1))) void*)(gp), \
                                     (__attribute__((address_space(3))) void*)(lp), 16, 0, 0)

// ---------------- CSR build ----------------
__global__ void k_deg(const int* __restrict__ dst, int* __restrict__ deg) {
    int e = blockIdx.x * 256 + threadIdx.x;
    if (e < N_EDGES) atomicAdd(&deg[dst[e]], 1);
}

__global__ void k_scan(const int* __restrict__ deg, int* __restrict__ offs) {
    __shared__ int s[1024];
    int t = threadIdx.x;
    int v[4]; int sum = 0;
#pragma unroll
    for (int i = 0; i < 4; i++) { v[i] = deg[t * 4 + i] + 1; sum += v[i]; }
    s[t] = sum; __syncthreads();
    for (int st = 1; st < 1024; st <<= 1) {
        int x = 0;
        if (t >= st) x = s[t - st];
        __syncthreads();
        s[t] += x;
        __syncthreads();
    }
    int run = s[t] - sum;
#pragma unroll
    for (int i = 0; i < 4; i++) { offs[t * 4 + i] = run; run += v[i]; }
    if (t == 1023) offs[N_NODES] = run;
}

__global__ void k_fill(const int* __restrict__ dst, const int* __restrict__ offs,
                       int* __restrict__ cur, int* __restrict__ csr) {
    int id = blockIdx.x * 256 + threadIdx.x;
    if (id >= EA_EDGES) return;
    int d = (id < N_EDGES) ? dst[id] : (id - N_EDGES);
    int p = atomicAdd(&cur[d], 1);
    csr[offs[d] + p] = id;
}

// ---------------- weight-side attention reductions (fp32 in, fp32 out) ----------------
__global__ void k_reduce_w(const float* __restrict__ W, const float* __restrict__ attA,
                           const float* __restrict__ attB, float* __restrict__ out,
                           int C, int col0) {
    int d = blockIdx.x, t = threadIdx.x;
    float acc[8] = {0, 0, 0, 0, 0, 0, 0, 0};
    for (int c = t; c < C; c += 256) {
#pragma unroll
        for (int h = 0; h < 4; h++) {
            float w = W[((size_t)d * 4 + h) * C + c];
            acc[h] += w * attA[h * C + c];
            if (attB) acc[4 + h] += w * attB[h * C + c];
        }
    }
    __shared__ float red[4][8];
    int lane = t & 63, wv = t >> 6;
#pragma unroll
    for (int j = 0; j < 8; j++) acc[j] = wsum(acc[j]);
    if (lane == 0) {
#pragma unroll
        for (int j = 0; j < 8; j++) red[wv][j] = acc[j];
    }
    __syncthreads();
    if (t < 8) {
        float s = red[0][t] + red[1][t] + red[2][t] + red[3][t];
        if (attB) out[d * 8 + col0 + t] = s;
        else if (t < 4) out[d * 8 + col0 + t] = s;
    }
}

// skinny GEMV: out[row][0..7] = X[row,:] @ Wr[:,0..7]   (one wave per row)
template <typename T>
__global__ void k_gemv8(const T* __restrict__ X, int K, const float* __restrict__ Wr,
                        float* __restrict__ out, int rows) {
    int wv = threadIdx.x >> 6, lane = threadIdx.x & 63;
    int row = blockIdx.x * 4 + wv;
    if (row >= rows) return;
    float acc[8] = {0, 0, 0, 0, 0, 0, 0, 0};
    const T* xp = X + (size_t)row * K;
    for (int k = lane; k < K; k += 64) {
        float xv = ldv(xp, k);
        const float* w = Wr + (size_t)k * 8;
#pragma unroll
        for (int j = 0; j < 8; j++) acc[j] += xv * w[j];
    }
#pragma unroll
    for (int j = 0; j < 8; j++) acc[j] = wsum(acc[j]);
    if (lane == 0) {
#pragma unroll
        for (int j = 0; j < 8; j++) out[(size_t)row * 8 + j] = acc[j];
    }
}

// self-loop edge attention = mean of incident real edges' a_e (linearity of mean_attr @ w)
__global__ void k_selfloop(float* __restrict__ ae, const int* __restrict__ csr,
                           const int* __restrict__ offs, const int* __restrict__ deg) {
    int n = blockIdx.x * 256 + threadIdx.x;
    if (n >= N_NODES) return;
    float s[8] = {0, 0, 0, 0, 0, 0, 0, 0};
    int lo = offs[n], hi = offs[n + 1];
    for (int i = lo; i < hi; i++) {
        int eid = csr[i];
        if (eid < N_EDGES) {
#pragma unroll
            for (int j = 0; j < 8; j++) s[j] += ae[(size_t)eid * 8 + j];
        }
    }
    float inv = 1.0f / (float)(deg[n] > 0 ? deg[n] : 1);
#pragma unroll
    for (int j = 0; j < 8; j++) ae[(size_t)(N_EDGES + n) * 8 + j] = s[j] * inv;
}

// per-dst-node attention softmax + aggregation in INPUT feature space:
// agg[n, d*4+h] = sum_e coef[e,h] * feat[src_e, d]  (bf16 out; column order = W's natural layout)
template <typename T>
__global__ void k_attn_agg(const T* __restrict__ feat, int D,
                           const float* __restrict__ asd, const float* __restrict__ ae, int aecol,
                           const int* __restrict__ offs, const int* __restrict__ csr,
                           const int* __restrict__ src, u16* __restrict__ agg) {
    int n = blockIdx.x, t = threadIdx.x;
    __shared__ int sl[MAXDEG];
    __shared__ float cf[MAXDEG][4];
    int lo = offs[n];
    int cnt = offs[n + 1] - lo;
    if (cnt > MAXDEG) cnt = MAXDEG;
    for (int i = t; i < cnt; i += 256) {
        int eid = csr[lo + i];
        int s = (eid < N_EDGES) ? src[eid] : n;
        sl[i] = s;
#pragma unroll
        for (int h = 0; h < 4; h++) {
            float al = asd[(size_t)s * 8 + h] + asd[(size_t)n * 8 + 4 + h] +
                       ae[(size_t)eid * 8 + aecol + h];
            cf[i][h] = (al >= 0.f) ? al : NEG_SLOPE * al;
        }
    }
    __syncthreads();
    if (t < 4) {   // head t: serial softmax over <= ~20 edges
        float mx = -1e30f;
        for (int i = 0; i < cnt; i++) mx = fmaxf(mx, cf[i][t]);
        float den = 0.f;
        for (int i = 0; i < cnt; i++) { float e = __expf(cf[i][t] - mx); cf[i][t] = e; den += e; }
        float inv = 1.0f / (den + 1e-16f);
        for (int i = 0; i < cnt; i++) cf[i][t] *= inv;
    }
    __syncthreads();
    for (int d = t; d < D; d += 256) {
        float a0 = 0, a1 = 0, a2 = 0, a3 = 0;
        for (int i = 0; i < cnt; i++) {
            float v = ldv(feat, (size_t)sl[i] * D + d);
            a0 += cf[i][0] * v; a1 += cf[i][1] * v; a2 += cf[i][2] * v; a3 += cf[i][3] * v;
        }
        ushort4 pk; pk.x = f2b(a0); pk.y = f2b(a1); pk.z = f2b(a2); pk.w = f2b(a3);
        *(ushort4*)(agg + (size_t)n * 4 * D + (size_t)d * 4) = pk;
    }
}

// ---------------- transpose + downcast (fp32 [R,C] -> bf16 [C,R]) ----------------
__global__ void k_transpose(const float* __restrict__ in, u16* __restrict__ out, int R, int C) {
    __shared__ float tile[64][65];
    int tx = threadIdx.x, ty = threadIdx.y;
    int rb = blockIdx.y * 64, cb = blockIdx.x * 64;
    for (int i = ty; i < 64; i += 4) tile[i][tx] = in[(size_t)(rb + i) * C + cb + tx];
    __syncthreads();
    for (int i = ty; i < 64; i += 4) out[(size_t)(cb + i) * R + rb + tx] = f2b(tile[tx][i]);
}

// ---------------- MFMA GEMM: C = prelu(scale * A@Bt^T + bias) ----------------
// A [M,K] bf16 row-major, Bt [N,K] bf16 row-major. 128xBN tile, BK=32, 4 waves.
// Staging mapping (R5 order + XOR swizzle): chunk c -> row = c>>2,
// kb = (c&3) ^ ((c>>3)&3). Measured facts driving this:
//  * R4 vs R5 vs R6: the global coalescer merges within 16-LANE GROUPS
//    (quarter-wave), not wave64 -- so 4 consecutive lanes must cover one 64B
//    line (R5 order; R6's {l,l+16,l+32,l+48} segmentation re-serialized the
//    address pipe, 135->197us).
//  * R5's un-swizzled layout had 8 lanes per LDS bank-quad on fragment reads
//    (1.26e7 conflict cycles ~ 15%). The kb XOR spreads fragment-read lanes
//    2-per-bank-quad (2-way = free, m136) while each staging quad still covers
//    one full (segment-permuted) 64B line.
// Fragment read: lane (rl = lane&15, q = lane>>4) reads chunk
// row*4 + (q ^ swz), swz = (rl>>1)&3 (wave-uniform per lane).
template <int BN>
__global__ __launch_bounds__(256, 2) void k_gemm(
        const u16* __restrict__ A, const u16* __restrict__ Bt, void* __restrict__ Cout,
        const float* __restrict__ bias, const float* __restrict__ prelu, float scale,
        int N, int K, int f32out) {
    constexpr int NJ = BN / 32;              // 16-wide n-subtiles per wave (2 waves along N)
    __shared__ __align__(16) u16 As[4096];       // 128 rows x 32 k (swizzled chunks), 8KB
    __shared__ __align__(16) u16 Bs[BN * 32];    // BN rows x 32 k (swizzled chunks)
    int tid = threadIdx.x;
    int lane = tid & 63, wv = tid >> 6;
    int m0 = blockIdx.y * 128, n0 = blockIdx.x * BN;
    int c0 = tid, c1 = tid + 256;
    // chunk c -> row = c>>2, kb = (c&3) ^ ((c>>3)&3)
    int r0c = c0 >> 2, k0c = (c0 & 3) ^ ((c0 >> 3) & 3);
    int r1c = c1 >> 2, k1c = (c1 & 3) ^ ((c1 >> 3) & 3);
    const u16* ag0 = A + (size_t)(m0 + r0c) * K + k0c * 8;
    const u16* ag1 = A + (size_t)(m0 + r1c) * K + k1c * 8;
    const u16* bg0 = Bt + (size_t)(n0 + r0c) * K + k0c * 8;
    const u16* bg1 = Bt + (size_t)(n0 + r1c) * K + k1c * 8;   // used only when BN==128
    u16* la0 = As + c0 * 8; u16* la1 = As + c1 * 8;
    u16* lb0 = Bs + c0 * 8; u16* lb1 = Bs + c1 * 8;           // lb1 only when BN==128
    int wm = wv & 1, wn = wv >> 1;
    int rl = lane & 15;
    int q = lane >> 4;
    int swz = (rl >> 1) & 3;
    int qa = q ^ swz;                          // swizzled k-chunk selector
    int mb = wm * 64 + rl;
    int nb = wn * (NJ * 16) + rl;
    f32x4 acc[4][NJ] = {};
    for (int k0 = 0; k0 < K; k0 += 32) {
        __syncthreads();                       // previous tile's LDS reads done
        GLD16(ag0, la0); GLD16(ag1, la1);
        GLD16(bg0, lb0);
        if (BN == 128) GLD16(bg1, lb1);
        ag0 += 32; ag1 += 32; bg0 += 32;
        if (BN == 128) bg1 += 32;
        __syncthreads();                       // drains vmcnt(0): staging landed
        bf16x8 af[4], bfr[NJ];
#pragma unroll
        for (int i = 0; i < 4; i++)            // chunk = (mb + i*16)*4 + qa
            af[i] = *(const bf16x8*)(As + (((mb + i * 16) * 4 + qa) * 8));
#pragma unroll
        for (int j = 0; j < NJ; j++)           // chunk = (nb + j*16)*4 + qa
            bfr[j] = *(const bf16x8*)(Bs + (((nb + j * 16) * 4 + qa) * 8));
#pragma unroll
        for (int i = 0; i < 4; i++)
#pragma unroll
            for (int j = 0; j < NJ; j++)
                acc[i][j] = __builtin_amdgcn_mfma_f32_16x16x32_bf16(af[i], bfr[j], acc[i][j], 0, 0, 0);
    }
    float pa = prelu[0];
    int r0w = (lane >> 4) * 4;
    int cc = lane & 15;
#pragma unroll
    for (int j = 0; j < NJ; j++) {
        int col = n0 + wn * (NJ * 16) + j * 16 + cc;
        float bv = bias[col];
#pragma unroll
        for (int i = 0; i < 4; i++) {
#pragma unroll
            for (int r = 0; r < 4; r++) {
                int row = m0 + wm * 64 + i * 16 + r0w + r;
                float v = acc[i][j][r] * scale + bv;
                v = (v >= 0.f) ? v : pa * v;
                if (f32out) ((float*)Cout)[(size_t)row * N + col] = v;
                else        ((u16*)Cout)[(size_t)row * N + col] = f2b(v);
            }
        }
    }
}

// ---------------- gate + pooling ----------------
__global__ void k_gate(const float* __restrict__ g2, const float* __restrict__ gW3,
                       const float* __restrict__ gb3, float* __restrict__ gate) {
    int wv = threadIdx.x >> 6, lane = threadIdx.x & 63;
    int n = blockIdx.x * 4 + wv;
    if (n >= N_NODES) return;
    float s = 0.f;
    for (int k = lane; k < HIDD; k += 64) s += g2[(size_t)n * HIDD + k] * gW3[k];
    s = wsum(s);
    if (lane == 0) gate[n] = s + gb3[0];
}

__global__ void k_pool(const float* __restrict__ gate, const u16* __restrict__ h2,
                       const int* __restrict__ batch, float* __restrict__ out) {
    int b = blockIdx.x, t = threadIdx.x;
    int lo = lower_bound(batch, N_NODES, b);
    int hi = lower_bound(batch, N_NODES, b + 1);
    int cnt = hi - lo;
    if (cnt <= 0) {
        for (int c = t; c < C2D; c += 256) out[(size_t)b * C2D + c] = 0.f;
        return;
    }
    if (cnt > 256) cnt = 256;   // multinomial(4096,1/64) max ~110; safety clamp
    __shared__ float w[256];
    __shared__ float red[4];
    int lane = t & 63, wv = t >> 6;
    float mx = -1e30f;
    for (int i = t; i < cnt; i += 256) mx = fmaxf(mx, gate[lo + i]);
    mx = wmax(mx);
    if (lane == 0) red[wv] = mx;
    __syncthreads();
    mx = fmaxf(fmaxf(red[0], red[1]), fmaxf(red[2], red[3]));
    __syncthreads();
    float ds = 0.f;
    for (int i = t; i < cnt; i += 256) { float e = __expf(gate[lo + i] - mx); w[i] = e; ds += e; }
    ds = wsum(ds);
    if (lane == 0) red[wv] = ds;
    __syncthreads();
    float inv = 1.0f / (red[0] + red[1] + red[2] + red[3] + 1e-16f);
    for (int c = t; c < C2D; c += 256) {
        float acc = 0.f;
        for (int i = 0; i < cnt; i++) acc += w[i] * b2f(h2[(size_t)(lo + i) * C2D + c]);
        out[(size_t)b * C2D + c] = acc * inv;
    }
}

// ---------------- launch ----------------
extern "C" void kernel_launch(void* const* d_in, const int* in_sizes, int n_in,
                              void* d_out, int out_size, void* d_ws, size_t ws_size,
                              hipStream_t stream) {
    (void)in_sizes; (void)n_in; (void)out_size; (void)ws_size;
    const float* x      = (const float*)d_in[0];
    const int*   eidx   = (const int*)d_in[1];
    const float* eattr  = (const float*)d_in[2];
    const int*   batch  = (const int*)d_in[3];
    const float* W1     = (const float*)d_in[4];
    const float* att_s1 = (const float*)d_in[5];
    const float* att_d1 = (const float*)d_in[6];
    const float* We1    = (const float*)d_in[7];
    const float* att_e1 = (const float*)d_in[8];
    const float* bias1  = (const float*)d_in[9];
    const float* prelu1 = (const float*)d_in[10];
    const float* W2     = (const float*)d_in[11];
    const float* att_s2 = (const float*)d_in[12];
    const float* att_d2 = (const float*)d_in[13];
    const float* We2    = (const float*)d_in[14];
    const float* att_e2 = (const float*)d_in[15];
    const float* bias2  = (const float*)d_in[16];
    const float* prelu2 = (const float*)d_in[17];
    const float* gW1    = (const float*)d_in[18];
    const float* gb1    = (const float*)d_in[19];
    const float* ga1    = (const float*)d_in[20];
    const float* gW2    = (const float*)d_in[21];
    const float* gb2    = (const float*)d_in[22];
    const float* ga2    = (const float*)d_in[23];
    const float* gW3    = (const float*)d_in[24];
    const float* gb3    = (const float*)d_in[25];
    const int* srcA = eidx;
    const int* dstA = eidx + N_EDGES;

    // ---- workspace (unions; total ~90 MB)
    char* wp = (char*)d_ws;
    auto alloc = [&](size_t bytes) -> void* {
        void* p = (void*)wp; wp += (bytes + 255) & ~(size_t)255; return p;
    };
    int*   deg  = (int*)alloc(N_NODES * 4);
    int*   cur  = (int*)alloc(N_NODES * 4);
    int*   offs = (int*)alloc((N_NODES + 1) * 4);
    int*   csr  = (int*)alloc(EA_EDGES * 4);
    float* vsd1 = (float*)alloc(CLIPD * 8 * 4);
    float* we12 = (float*)alloc(CLIPD * 8 * 4);
    float* vsd2 = (float*)alloc(HIDD * 8 * 4);
    float* ae   = (float*)alloc((size_t)EA_EDGES * 8 * 4);
    float* asd1 = (float*)alloc((size_t)N_NODES * 8 * 4);
    float* asd2 = (float*)alloc((size_t)N_NODES * 8 * 4);
    float* gate = (float*)alloc(N_NODES * 4);
    // union 1 (32MB): agg1 [N,3072]bf16 / agg2 [N,4096]bf16 / g2 [N,1024]f32
    char*  aggU = (char*)alloc((size_t)N_NODES * 4096 * 2);
    u16*   agg1 = (u16*)aggU;
    u16*   agg2 = (u16*)aggU;
    float* g2   = (float*)aggU;
    // union 2 (8MB): h1 / g1 (h1 dead before g1 written)
    u16*   h1   = (u16*)alloc((size_t)N_NODES * HIDD * 2);
    u16*   g1   = h1;
    u16*   h2   = (u16*)alloc((size_t)N_NODES * C2D * 2);          // 24MB
    u16*   Btb  = (u16*)alloc((size_t)C2D * 4096 * 2);             // 24MB shared B^T buf

    hipMemsetAsync(deg, 0, N_NODES * 4, stream);
    hipMemsetAsync(cur, 0, N_NODES * 4, stream);

    // CSR by dst (includes self loops)
    k_deg<<<(N_EDGES + 255) / 256, 256, 0, stream>>>(dstA, deg);
    k_scan<<<1, 1024, 0, stream>>>(deg, offs);
    k_fill<<<(EA_EDGES + 255) / 256, 256, 0, stream>>>(dstA, offs, cur, csr);

    // weight-side reductions: vsd1=[W1.att_src1|W1.att_dst1], we12=[We1.att_e1|We2.att_e2], vsd2 likewise
    k_reduce_w<<<CLIPD, 256, 0, stream>>>(W1, att_s1, att_d1, vsd1, HIDD, 0);
    k_reduce_w<<<CLIPD, 256, 0, stream>>>(We1, att_e1, nullptr, we12, HIDD, 0);
    k_reduce_w<<<HIDD, 256, 0, stream>>>(W2, att_s2, att_d2, vsd2, C2D, 0);
    k_reduce_w<<<CLIPD, 256, 0, stream>>>(We2, att_e2, nullptr, we12, C2D, 4);

    // edge attention logits for both layers; self-loop rows = incident mean (linearity)
    k_gemv8<float><<<N_EDGES / 4, 256, 0, stream>>>(eattr, CLIPD, we12, ae, N_EDGES);
    k_selfloop<<<(N_NODES + 255) / 256, 256, 0, stream>>>(ae, csr, offs, deg);
    k_gemv8<float><<<N_NODES / 4, 256, 0, stream>>>(x, CLIPD, vsd1, asd1, N_NODES);

    // ---- layer 1: aggregate in input space, then one fused GEMM (head-mean=0.25, bias, prelu)
    k_attn_agg<float><<<N_NODES, 256, 0, stream>>>(x, CLIPD, asd1, ae, 0, offs, csr, srcA, agg1);
    k_transpose<<<dim3(HIDD / 64, C2D / 64), dim3(64, 4), 0, stream>>>(W1, Btb, C2D, HIDD);
    k_gemm<64><<<dim3(HIDD / 64, N_NODES / 128), 256, 0, stream>>>(
        agg1, Btb, h1, bias1, prelu1, 0.25f, HIDD, C2D, 0);

    // ---- layer 2
    k_gemv8<u16><<<N_NODES / 4, 256, 0, stream>>>(h1, HIDD, vsd2, asd2, N_NODES);
    k_attn_agg<u16><<<N_NODES, 256, 0, stream>>>(h1, HIDD, asd2, ae, 4, offs, csr, srcA, agg2);
    k_transpose<<<dim3(C2D / 64, 4096 / 64), dim3(64, 4), 0, stream>>>(W2, Btb, 4096, C2D);
    k_gemm<128><<<dim3(C2D / 128, N_NODES / 128), 256, 0, stream>>>(
        agg2, Btb, h2, bias2, prelu2, 0.25f, C2D, 4096, 0);

    // ---- gate MLP (g2 kept fp32 for the softmax path)
    k_transpose<<<dim3(HIDD / 64, C2D / 64), dim3(64, 4), 0, stream>>>(gW1, Btb, C2D, HIDD);
    k_gemm<64><<<dim3(HIDD / 64, N_NODES / 128), 256, 0, stream>>>(
        h2, Btb, g1, gb1, ga1, 1.0f, HIDD, C2D, 0);
    k_transpose<<<dim3(HIDD / 64, HIDD / 64), dim3(64, 4), 0, stream>>>(gW2, Btb, HIDD, HIDD);
    k_gemm<64><<<dim3(HIDD / 64, N_NODES / 128), 256, 0, stream>>>(
        g1, Btb, (void*)g2, gb2, ga2, 1.0f, HIDD, HIDD, 1);
    k_gate<<<N_NODES / 4, 256, 0, stream>>>(g2, gW3, gb3, gate);

    // ---- attentional pooling over sorted batch (fp32 output)
    k_pool<<<NBATCH, 256, 0, stream>>>(gate, h2, batch, (float*)d_out);
}

// Round 8
// 666.153 us; speedup vs baseline: 1.2278x; 1.0666x over previous
//
#include <hip/hip_runtime.h>
#include <stdint.h>
#include <stddef.h>

// ---------------- problem constants ----------------
#define N_NODES  4096
#define N_EDGES  12288
#define EA_EDGES 16384      // N_EDGES + N_NODES self loops
#define NBATCH   64
#define CLIPD    768
#define HIDD     1024
#define C2D      3072
#define NEG_SLOPE 0.2f
#define MAXDEG   96         // in-degree ~Poisson(3); P(>96) ~ 0

typedef unsigned short u16;
typedef short bf16x8 __attribute__((ext_vector_type(8)));   // 8 bf16 = 4 VGPRs (guide §3)
typedef float f32x4  __attribute__((ext_vector_type(4)));

static __device__ __forceinline__ float b2f(u16 u) {
    union { float f; unsigned int i; } v; v.i = ((unsigned int)u) << 16; return v.f;
}
static __device__ __forceinline__ u16 f2b(float f) {
    union { float f; unsigned int i; } v; v.f = f;
    unsigned int r = (v.i + 0x7fffu + ((v.i >> 16) & 1u)) >> 16;   // RNE
    return (u16)r;
}
// dtype-polymorphic element load (inputs are fp32; internal tensors bf16)
static __device__ __forceinline__ float ldv(const float* p, size_t i) { return p[i]; }
static __device__ __forceinline__ float ldv(const u16* p, size_t i)   { return b2f(p[i]); }

static __device__ __forceinline__ float wsum(float v) {
#pragma unroll
    for (int o = 32; o > 0; o >>= 1) v += __shfl_xor(v, o, 64);
    return v;
}
static __device__ __forceinline__ float wmax(float v) {
#pragma unroll
    for (int o = 32; o > 0; o >>= 1) v = fmaxf(v, __shfl_xor(v, o, 64));
    return v;
}
static __device__ __forceinline__ int lower_bound(const int* a, int n, int key) {
    int lo = 0, hi = n;
    while (lo < hi) { int m = (lo + hi) >> 1; if (a[m] < key) lo = m + 1; else hi = m; }
    return lo;
}

// async global->LDS, 16B per lane. LDS dst is wave-uniform base + lane*16 (m104/m108);
// our LDS offsets are exactly tid*16, satisfying that constraint.
#define GLD16(gp, lp)                                                            \
    __builtin_amdgcn_global_load_lds((const __attribute__((address_space(1))) void*)(gp), \
                                     (__attribute__((address_space(3))) void*)(lp), 16, 0, 0)

// ---------------- CSR build ----------------
__global__ void k_deg(const int* __restrict__ dst, int* __restrict__ deg) {
    int e = blockIdx.x * 256 + threadIdx.x;
    if (e < N_EDGES) atomicAdd(&deg[dst[e]], 1);
}

__global__ void k_scan(const int* __restrict__ deg, int* __restrict__ offs) {
    __shared__ int s[1024];
    int t = threadIdx.x;
    int v[4]; int sum = 0;
#pragma unroll
    for (int i = 0; i < 4; i++) { v[i] = deg[t * 4 + i] + 1; sum += v[i]; }
    s[t] = sum; __syncthreads();
    for (int st = 1; st < 1024; st <<= 1) {
        int x = 0;
        if (t >= st) x = s[t - st];
        __syncthreads();
        s[t] += x;
        __syncthreads();
    }
    int run = s[t] - sum;
#pragma unroll
    for (int i = 0; i < 4; i++) { offs[t * 4 + i] = run; run += v[i]; }
    if (t == 1023) offs[N_NODES] = run;
}

__global__ void k_fill(const int* __restrict__ dst, const int* __restrict__ offs,
                       int* __restrict__ cur, int* __restrict__ csr) {
    int id = blockIdx.x * 256 + threadIdx.x;
    if (id >= EA_EDGES) return;
    int d = (id < N_EDGES) ? dst[id] : (id - N_EDGES);
    int p = atomicAdd(&cur[d], 1);
    csr[offs[d] + p] = id;
}

// ---------------- weight-side attention reductions (fp32 in, fp32 out) ----------------
__global__ void k_reduce_w(const float* __restrict__ W, const float* __restrict__ attA,
                           const float* __restrict__ attB, float* __restrict__ out,
                           int C, int col0) {
    int d = blockIdx.x, t = threadIdx.x;
    float acc[8] = {0, 0, 0, 0, 0, 0, 0, 0};
    for (int c = t; c < C; c += 256) {
#pragma unroll
        for (int h = 0; h < 4; h++) {
            float w = W[((size_t)d * 4 + h) * C + c];
            acc[h] += w * attA[h * C + c];
            if (attB) acc[4 + h] += w * attB[h * C + c];
        }
    }
    __shared__ float red[4][8];
    int lane = t & 63, wv = t >> 6;
#pragma unroll
    for (int j = 0; j < 8; j++) acc[j] = wsum(acc[j]);
    if (lane == 0) {
#pragma unroll
        for (int j = 0; j < 8; j++) red[wv][j] = acc[j];
    }
    __syncthreads();
    if (t < 8) {
        float s = red[0][t] + red[1][t] + red[2][t] + red[3][t];
        if (attB) out[d * 8 + col0 + t] = s;
        else if (t < 4) out[d * 8 + col0 + t] = s;
    }
}

// skinny GEMV: out[row][0..7] = X[row,:] @ Wr[:,0..7]   (one wave per row)
template <typename T>
__global__ void k_gemv8(const T* __restrict__ X, int K, const float* __restrict__ Wr,
                        float* __restrict__ out, int rows) {
    int wv = threadIdx.x >> 6, lane = threadIdx.x & 63;
    int row = blockIdx.x * 4 + wv;
    if (row >= rows) return;
    float acc[8] = {0, 0, 0, 0, 0, 0, 0, 0};
    const T* xp = X + (size_t)row * K;
    for (int k = lane; k < K; k += 64) {
        float xv = ldv(xp, k);
        const float* w = Wr + (size_t)k * 8;
#pragma unroll
        for (int j = 0; j < 8; j++) acc[j] += xv * w[j];
    }
#pragma unroll
    for (int j = 0; j < 8; j++) acc[j] = wsum(acc[j]);
    if (lane == 0) {
#pragma unroll
        for (int j = 0; j < 8; j++) out[(size_t)row * 8 + j] = acc[j];
    }
}

// self-loop edge attention = mean of incident real edges' a_e (linearity of mean_attr @ w)
__global__ void k_selfloop(float* __restrict__ ae, const int* __restrict__ csr,
                           const int* __restrict__ offs, const int* __restrict__ deg) {
    int n = blockIdx.x * 256 + threadIdx.x;
    if (n >= N_NODES) return;
    float s[8] = {0, 0, 0, 0, 0, 0, 0, 0};
    int lo = offs[n], hi = offs[n + 1];
    for (int i = lo; i < hi; i++) {
        int eid = csr[i];
        if (eid < N_EDGES) {
#pragma unroll
            for (int j = 0; j < 8; j++) s[j] += ae[(size_t)eid * 8 + j];
        }
    }
    float inv = 1.0f / (float)(deg[n] > 0 ? deg[n] : 1);
#pragma unroll
    for (int j = 0; j < 8; j++) ae[(size_t)(N_EDGES + n) * 8 + j] = s[j] * inv;
}

// per-dst-node attention softmax + aggregation in INPUT feature space:
// agg[n, d*4+h] = sum_e coef[e,h] * feat[src_e, d]  (bf16 out; column order = W's natural layout)
template <typename T>
__global__ void k_attn_agg(const T* __restrict__ feat, int D,
                           const float* __restrict__ asd, const float* __restrict__ ae, int aecol,
                           const int* __restrict__ offs, const int* __restrict__ csr,
                           const int* __restrict__ src, u16* __restrict__ agg) {
    int n = blockIdx.x, t = threadIdx.x;
    __shared__ int sl[MAXDEG];
    __shared__ float cf[MAXDEG][4];
    int lo = offs[n];
    int cnt = offs[n + 1] - lo;
    if (cnt > MAXDEG) cnt = MAXDEG;
    for (int i = t; i < cnt; i += 256) {
        int eid = csr[lo + i];
        int s = (eid < N_EDGES) ? src[eid] : n;
        sl[i] = s;
#pragma unroll
        for (int h = 0; h < 4; h++) {
            float al = asd[(size_t)s * 8 + h] + asd[(size_t)n * 8 + 4 + h] +
                       ae[(size_t)eid * 8 + aecol + h];
            cf[i][h] = (al >= 0.f) ? al : NEG_SLOPE * al;
        }
    }
    __syncthreads();
    if (t < 4) {   // head t: serial softmax over <= ~20 edges
        float mx = -1e30f;
        for (int i = 0; i < cnt; i++) mx = fmaxf(mx, cf[i][t]);
        float den = 0.f;
        for (int i = 0; i < cnt; i++) { float e = __expf(cf[i][t] - mx); cf[i][t] = e; den += e; }
        float inv = 1.0f / (den + 1e-16f);
        for (int i = 0; i < cnt; i++) cf[i][t] *= inv;
    }
    __syncthreads();
    for (int d = t; d < D; d += 256) {
        float a0 = 0, a1 = 0, a2 = 0, a3 = 0;
        for (int i = 0; i < cnt; i++) {
            float v = ldv(feat, (size_t)sl[i] * D + d);
            a0 += cf[i][0] * v; a1 += cf[i][1] * v; a2 += cf[i][2] * v; a3 += cf[i][3] * v;
        }
        ushort4 pk; pk.x = f2b(a0); pk.y = f2b(a1); pk.z = f2b(a2); pk.w = f2b(a3);
        *(ushort4*)(agg + (size_t)n * 4 * D + (size_t)d * 4) = pk;
    }
}

// ---------------- transpose + downcast (fp32 [R,C] -> bf16 [C,R]) ----------------
__global__ void k_transpose(const float* __restrict__ in, u16* __restrict__ out, int R, int C) {
    __shared__ float tile[64][65];
    int tx = threadIdx.x, ty = threadIdx.y;
    int rb = blockIdx.y * 64, cb = blockIdx.x * 64;
    for (int i = ty; i < 64; i += 4) tile[i][tx] = in[(size_t)(rb + i) * C + cb + tx];
    __syncthreads();
    for (int i = ty; i < 64; i += 4) out[(size_t)(cb + i) * R + rb + tx] = f2b(tile[tx][i]);
}

// ---------------- MFMA GEMM: C = prelu(scale * A@Bt^T + bias) ----------------
// A [M,K] bf16 row-major, Bt [N,K] bf16 row-major. 128xBN tile, BK=64, 4 waves.
// BK=64 (R7->R8): halves barrier count per kernel (the m97-structure stall is the
// vmcnt(0)+s_barrier drain; m132's BK=128 regression was an occupancy cliff at
// 64KB LDS -- at 32KB/24KB we keep 5-6 blocks/CU >= the grid-imposed 3/2, so
// occupancy is unchanged while MFMA-per-barrier doubles).
// Chunk mapping: c -> row = c>>3, kb = (c&7) ^ (row&7).
//  * staging: lane-quads are 4-aligned in c, same row, kb = {0..3}^m or {4..7}^m
//    = one contiguous 64B half-line (XOR permutes within / flips halves) -- keeps
//    the R5 quarter-wave coalescing (the coalescer merges per 16-lane group).
//  * fragment read: lane (rl,q), k-half s reads chunk row*8 + ((q+4s)^(rl&7));
//    bank-quad = (q+4s)^(rl&7) covers all 8 quads, 2 lanes each = free (m136).
template <int BN>
__global__ __launch_bounds__(256, 2) void k_gemm(
        const u16* __restrict__ A, const u16* __restrict__ Bt, void* __restrict__ Cout,
        const float* __restrict__ bias, const float* __restrict__ prelu, float scale,
        int N, int K, int f32out) {
    constexpr int NJ = BN / 32;              // 16-wide n-subtiles per wave (2 waves along N)
    constexpr int NBCH = BN * 8 / 256;       // B chunks per thread (4 or 2)
    __shared__ __align__(16) u16 As[128 * 64];   // 16 KB
    __shared__ __align__(16) u16 Bs[BN * 64];    // 16 KB (BN=128) / 8 KB (BN=64)
    int tid = threadIdx.x;
    int lane = tid & 63, wv = tid >> 6;
    int m0 = blockIdx.y * 128, n0 = blockIdx.x * BN;
    const u16* agp[4]; u16* alp[4];
#pragma unroll
    for (int u = 0; u < 4; u++) {
        int c = tid + u * 256;
        int r = c >> 3, kb = (c & 7) ^ (r & 7);
        agp[u] = A + (size_t)(m0 + r) * K + kb * 8;
        alp[u] = As + c * 8;
    }
    const u16* bgp[NBCH]; u16* blp[NBCH];
#pragma unroll
    for (int u = 0; u < NBCH; u++) {
        int c = tid + u * 256;
        int r = c >> 3, kb = (c & 7) ^ (r & 7);
        bgp[u] = Bt + (size_t)(n0 + r) * K + kb * 8;
        blp[u] = Bs + c * 8;
    }
    int wm = wv & 1, wn = wv >> 1;
    int rl = lane & 15, q = lane >> 4;
    int swz = rl & 7;
    int mb = wm * 64 + rl;
    int nb = wn * (NJ * 16) + rl;
    f32x4 acc[4][NJ] = {};
    for (int k0 = 0; k0 < K; k0 += 64) {
        __syncthreads();                       // previous tile's LDS reads done
#pragma unroll
        for (int u = 0; u < 4; u++) { GLD16(agp[u], alp[u]); agp[u] += 64; }
#pragma unroll
        for (int u = 0; u < NBCH; u++) { GLD16(bgp[u], blp[u]); bgp[u] += 64; }
        __syncthreads();                       // drains vmcnt(0): staging landed
        bf16x8 af[4][2], bfr[NJ][2];
#pragma unroll
        for (int i = 0; i < 4; i++)
#pragma unroll
            for (int s = 0; s < 2; s++)
                af[i][s] = *(const bf16x8*)(As + (((mb + i * 16) * 8 + ((q + 4 * s) ^ swz)) * 8));
#pragma unroll
        for (int j = 0; j < NJ; j++)
#pragma unroll
            for (int s = 0; s < 2; s++)
                bfr[j][s] = *(const bf16x8*)(Bs + (((nb + j * 16) * 8 + ((q + 4 * s) ^ swz)) * 8));
#pragma unroll
        for (int i = 0; i < 4; i++)
#pragma unroll
            for (int j = 0; j < NJ; j++) {
                acc[i][j] = __builtin_amdgcn_mfma_f32_16x16x32_bf16(af[i][0], bfr[j][0], acc[i][j], 0, 0, 0);
                acc[i][j] = __builtin_amdgcn_mfma_f32_16x16x32_bf16(af[i][1], bfr[j][1], acc[i][j], 0, 0, 0);
            }
    }
    float pa = prelu[0];
    int r0w = (lane >> 4) * 4;
    int cc = lane & 15;
#pragma unroll
    for (int j = 0; j < NJ; j++) {
        int col = n0 + wn * (NJ * 16) + j * 16 + cc;
        float bv = bias[col];
#pragma unroll
        for (int i = 0; i < 4; i++) {
#pragma unroll
            for (int r = 0; r < 4; r++) {
                int row = m0 + wm * 64 + i * 16 + r0w + r;
                float v = acc[i][j][r] * scale + bv;
                v = (v >= 0.f) ? v : pa * v;
                if (f32out) ((float*)Cout)[(size_t)row * N + col] = v;
                else        ((u16*)Cout)[(size_t)row * N + col] = f2b(v);
            }
        }
    }
}

// ---------------- gate + pooling ----------------
__global__ void k_gate(const float* __restrict__ g2, const float* __restrict__ gW3,
                       const float* __restrict__ gb3, float* __restrict__ gate) {
    int wv = threadIdx.x >> 6, lane = threadIdx.x & 63;
    int n = blockIdx.x * 4 + wv;
    if (n >= N_NODES) return;
    float s = 0.f;
    for (int k = lane; k < HIDD; k += 64) s += g2[(size_t)n * HIDD + k] * gW3[k];
    s = wsum(s);
    if (lane == 0) gate[n] = s + gb3[0];
}

__global__ void k_pool(const float* __restrict__ gate, const u16* __restrict__ h2,
                       const int* __restrict__ batch, float* __restrict__ out) {
    int b = blockIdx.x, t = threadIdx.x;
    int lo = lower_bound(batch, N_NODES, b);
    int hi = lower_bound(batch, N_NODES, b + 1);
    int cnt = hi - lo;
    if (cnt <= 0) {
        for (int c = t; c < C2D; c += 256) out[(size_t)b * C2D + c] = 0.f;
        return;
    }
    if (cnt > 256) cnt = 256;   // multinomial(4096,1/64) max ~110; safety clamp
    __shared__ float w[256];
    __shared__ float red[4];
    int lane = t & 63, wv = t >> 6;
    float mx = -1e30f;
    for (int i = t; i < cnt; i += 256) mx = fmaxf(mx, gate[lo + i]);
    mx = wmax(mx);
    if (lane == 0) red[wv] = mx;
    __syncthreads();
    mx = fmaxf(fmaxf(red[0], red[1]), fmaxf(red[2], red[3]));
    __syncthreads();
    float ds = 0.f;
    for (int i = t; i < cnt; i += 256) { float e = __expf(gate[lo + i] - mx); w[i] = e; ds += e; }
    ds = wsum(ds);
    if (lane == 0) red[wv] = ds;
    __syncthreads();
    float inv = 1.0f / (red[0] + red[1] + red[2] + red[3] + 1e-16f);
    for (int c = t; c < C2D; c += 256) {
        float acc = 0.f;
        for (int i = 0; i < cnt; i++) acc += w[i] * b2f(h2[(size_t)(lo + i) * C2D + c]);
        out[(size_t)b * C2D + c] = acc * inv;
    }
}

// ---------------- launch ----------------
extern "C" void kernel_launch(void* const* d_in, const int* in_sizes, int n_in,
                              void* d_out, int out_size, void* d_ws, size_t ws_size,
                              hipStream_t stream) {
    (void)in_sizes; (void)n_in; (void)out_size; (void)ws_size;
    const float* x      = (const float*)d_in[0];
    const int*   eidx   = (const int*)d_in[1];
    const float* eattr  = (const float*)d_in[2];
    const int*   batch  = (const int*)d_in[3];
    const float* W1     = (const float*)d_in[4];
    const float* att_s1 = (const float*)d_in[5];
    const float* att_d1 = (const float*)d_in[6];
    const float* We1    = (const float*)d_in[7];
    const float* att_e1 = (const float*)d_in[8];
    const float* bias1  = (const float*)d_in[9];
    const float* prelu1 = (const float*)d_in[10];
    const float* W2     = (const float*)d_in[11];
    const float* att_s2 = (const float*)d_in[12];
    const float* att_d2 = (const float*)d_in[13];
    const float* We2    = (const float*)d_in[14];
    const float* att_e2 = (const float*)d_in[15];
    const float* bias2  = (const float*)d_in[16];
    const float* prelu2 = (const float*)d_in[17];
    const float* gW1    = (const float*)d_in[18];
    const float* gb1    = (const float*)d_in[19];
    const float* ga1    = (const float*)d_in[20];
    const float* gW2    = (const float*)d_in[21];
    const float* gb2    = (const float*)d_in[22];
    const float* ga2    = (const float*)d_in[23];
    const float* gW3    = (const float*)d_in[24];
    const float* gb3    = (const float*)d_in[25];
    const int* srcA = eidx;
    const int* dstA = eidx + N_EDGES;

    // ---- workspace (unions; total ~90 MB)
    char* wp = (char*)d_ws;
    auto alloc = [&](size_t bytes) -> void* {
        void* p = (void*)wp; wp += (bytes + 255) & ~(size_t)255; return p;
    };
    int*   deg  = (int*)alloc(N_NODES * 4);
    int*   cur  = (int*)alloc(N_NODES * 4);
    int*   offs = (int*)alloc((N_NODES + 1) * 4);
    int*   csr  = (int*)alloc(EA_EDGES * 4);
    float* vsd1 = (float*)alloc(CLIPD * 8 * 4);
    float* we12 = (float*)alloc(CLIPD * 8 * 4);
    float* vsd2 = (float*)alloc(HIDD * 8 * 4);
    float* ae   = (float*)alloc((size_t)EA_EDGES * 8 * 4);
    float* asd1 = (float*)alloc((size_t)N_NODES * 8 * 4);
    float* asd2 = (float*)alloc((size_t)N_NODES * 8 * 4);
    float* gate = (float*)alloc(N_NODES * 4);
    // union 1 (32MB): agg1 [N,3072]bf16 / agg2 [N,4096]bf16 / g2 [N,1024]f32
    char*  aggU = (char*)alloc((size_t)N_NODES * 4096 * 2);
    u16*   agg1 = (u16*)aggU;
    u16*   agg2 = (u16*)aggU;
    float* g2   = (float*)aggU;
    // union 2 (8MB): h1 / g1 (h1 dead before g1 written)
    u16*   h1   = (u16*)alloc((size_t)N_NODES * HIDD * 2);
    u16*   g1   = h1;
    u16*   h2   = (u16*)alloc((size_t)N_NODES * C2D * 2);          // 24MB
    u16*   Btb  = (u16*)alloc((size_t)C2D * 4096 * 2);             // 24MB shared B^T buf

    hipMemsetAsync(deg, 0, N_NODES * 4, stream);
    hipMemsetAsync(cur, 0, N_NODES * 4, stream);

    // CSR by dst (includes self loops)
    k_deg<<<(N_EDGES + 255) / 256, 256, 0, stream>>>(dstA, deg);
    k_scan<<<1, 1024, 0, stream>>>(deg, offs);
    k_fill<<<(EA_EDGES + 255) / 256, 256, 0, stream>>>(dstA, offs, cur, csr);

    // weight-side reductions: vsd1=[W1.att_src1|W1.att_dst1], we12=[We1.att_e1|We2.att_e2], vsd2 likewise
    k_reduce_w<<<CLIPD, 256, 0, stream>>>(W1, att_s1, att_d1, vsd1, HIDD, 0);
    k_reduce_w<<<CLIPD, 256, 0, stream>>>(We1, att_e1, nullptr, we12, HIDD, 0);
    k_reduce_w<<<HIDD, 256, 0, stream>>>(W2, att_s2, att_d2, vsd2, C2D, 0);
    k_reduce_w<<<CLIPD, 256, 0, stream>>>(We2, att_e2, nullptr, we12, C2D, 4);

    // edge attention logits for both layers; self-loop rows = incident mean (linearity)
    k_gemv8<float><<<N_EDGES / 4, 256, 0, stream>>>(eattr, CLIPD, we12, ae, N_EDGES);
    k_selfloop<<<(N_NODES + 255) / 256, 256, 0, stream>>>(ae, csr, offs, deg);
    k_gemv8<float><<<N_NODES / 4, 256, 0, stream>>>(x, CLIPD, vsd1, asd1, N_NODES);

    // ---- layer 1: aggregate in input space, then one fused GEMM (head-mean=0.25, bias, prelu)
    k_attn_agg<float><<<N_NODES, 256, 0, stream>>>(x, CLIPD, asd1, ae, 0, offs, csr, srcA, agg1);
    k_transpose<<<dim3(HIDD / 64, C2D / 64), dim3(64, 4), 0, stream>>>(W1, Btb, C2D, HIDD);
    k_gemm<64><<<dim3(HIDD / 64, N_NODES / 128), 256, 0, stream>>>(
        agg1, Btb, h1, bias1, prelu1, 0.25f, HIDD, C2D, 0);

    // ---- layer 2
    k_gemv8<u16><<<N_NODES / 4, 256, 0, stream>>>(h1, HIDD, vsd2, asd2, N_NODES);
    k_attn_agg<u16><<<N_NODES, 256, 0, stream>>>(h1, HIDD, asd2, ae, 4, offs, csr, srcA, agg2);
    k_transpose<<<dim3(C2D / 64, 4096 / 64), dim3(64, 4), 0, stream>>>(W2, Btb, 4096, C2D);
    k_gemm<128><<<dim3(C2D / 128, N_NODES / 128), 256, 0, stream>>>(
        agg2, Btb, h2, bias2, prelu2, 0.25f, C2D, 4096, 0);

    // ---- gate MLP (g2 kept fp32 for the softmax path)
    k_transpose<<<dim3(HIDD / 64, C2D / 64), dim3(64, 4), 0, stream>>>(gW1, Btb, C2D, HIDD);
    k_gemm<64><<<dim3(HIDD / 64, N_NODES / 128), 256, 0, stream>>>(
        h2, Btb, g1, gb1, ga1, 1.0f, HIDD, C2D, 0);
    k_transpose<<<dim3(HIDD / 64, HIDD / 64), dim3(64, 4), 0, stream>>>(gW2, Btb, HIDD, HIDD);
    k_gemm<64><<<dim3(HIDD / 64, N_NODES / 128), 256, 0, stream>>>(
        g1, Btb, (void*)g2, gb2, ga2, 1.0f, HIDD, HIDD, 1);
    k_gate<<<N_NODES / 4, 256, 0, stream>>>(g2, gW3, gb3, gate);

    // ---- attentional pooling over sorted batch (fp32 output)
    k_pool<<<NBATCH, 256, 0, stream>>>(gate, h2, batch, (float*)d_out);
}